// Round 1
// baseline (390.624 us; speedup 1.0000x reference)
//
#include <hip/hip_runtime.h>

// IFOPooling: h_t = f_t * h_{t-1} + i_t * z_t along S (contiguous axis).
// Layout [B=16, H=1024, S=2048] fp32.
//
// One WAVE per (b,h) row — no LDS, no __syncthreads. A row (2048 floats) is
// 8 sub-blocks of 256 floats; in sub-block k, lane l owns the contiguous
// float4 at index k*64+l (perfectly coalesced 1 KiB wave loads). Each
// sub-block is reduced to a per-lane affine op (A,B), shuffle-scanned within
// the wave (the 8 scans are independent -> ILP), and an 8-step serial carry
// chain links sub-blocks. Waves are fully independent, so load phases of
// co-resident waves stagger and keep the HBM pipe busy (the previous
// block-wide barrier+LDS structure idled memory ~40% of the time).

constexpr int S_LEN  = 2048;
constexpr int WAVES  = 4;            // independent waves per block
constexpr int TPB    = 64 * WAVES;   // 256 threads
constexpr int K_SUB  = S_LEN / 256;  // 8 sub-blocks of 256 floats

__global__ __launch_bounds__(TPB) void ifo_scan_kernel(
    const float* __restrict__ f,
    const float* __restrict__ z,
    const float* __restrict__ iin,
    float* __restrict__ out,
    int n_rows)
{
    const int lane = threadIdx.x & 63;
    const int wv   = threadIdx.x >> 6;
    const size_t row = (size_t)blockIdx.x * WAVES + wv;
    if (row >= (size_t)n_rows) return;
    const size_t base = row * S_LEN;

    const float4* __restrict__ F = reinterpret_cast<const float4*>(f   + base);
    const float4* __restrict__ Z = reinterpret_cast<const float4*>(z   + base);
    const float4* __restrict__ I = reinterpret_cast<const float4*>(iin + base);
    float4* __restrict__ O = reinterpret_cast<float4*>(out + base);

    // Issue all loads up front (24 independent dwordx4 -> deep MLP per wave).
    float4 ff[K_SUB], xx[K_SUB];
    #pragma unroll
    for (int k = 0; k < K_SUB; ++k) {
        ff[k] = F[k * 64 + lane];
        const float4 zz = Z[k * 64 + lane];
        const float4 ii = I[k * 64 + lane];
        xx[k].x = ii.x * zz.x;
        xx[k].y = ii.y * zz.y;
        xx[k].z = ii.z * zz.z;
        xx[k].w = ii.w * zz.w;
    }

    // Per-lane 4-element chunk composition: h_out = A*h_in + B
    float a[K_SUB], b[K_SUB];
    #pragma unroll
    for (int k = 0; k < K_SUB; ++k) {
        float A = ff[k].x, B = xx[k].x;
        A = ff[k].y * A;  B = ff[k].y * B + xx[k].y;
        A = ff[k].z * A;  B = ff[k].z * B + xx[k].z;
        A = ff[k].w * A;  B = ff[k].w * B + xx[k].w;
        a[k] = A; b[k] = B;
    }

    // Wave-level inclusive scans under affine composition.
    // The K_SUB scans are independent -> the 6-step shuffle chains interleave.
    #pragma unroll
    for (int k = 0; k < K_SUB; ++k) {
        #pragma unroll
        for (int d = 1; d < 64; d <<= 1) {
            float a_up = __shfl_up(a[k], d);
            float b_up = __shfl_up(b[k], d);
            if (lane >= d) {
                b[k] = a[k] * b_up + b[k];   // apply current after previous
                a[k] = a[k] * a_up;
            }
        }
    }

    // Serial carry across sub-blocks + per-lane replay/store.
    float h_carry = 0.0f;   // h_{-1} = 0
    #pragma unroll
    for (int k = 0; k < K_SUB; ++k) {
        // exclusive prefix for this lane within sub-block k
        float ea = __shfl_up(a[k], 1);
        float eb = __shfl_up(b[k], 1);
        if (lane == 0) { ea = 1.0f; eb = 0.0f; }
        float h = ea * h_carry + eb;

        // sub-block total (inclusive at lane 63) -> carry into next sub-block
        const float ta = __shfl(a[k], 63);
        const float tb = __shfl(b[k], 63);
        const float next = ta * h_carry + tb;

        float4 oo;
        h = ff[k].x * h + xx[k].x;  oo.x = h;
        h = ff[k].y * h + xx[k].y;  oo.y = h;
        h = ff[k].z * h + xx[k].z;  oo.z = h;
        h = ff[k].w * h + xx[k].w;  oo.w = h;
        O[k * 64 + lane] = oo;

        h_carry = next;
    }
}

extern "C" void kernel_launch(void* const* d_in, const int* in_sizes, int n_in,
                              void* d_out, int out_size, void* d_ws, size_t ws_size,
                              hipStream_t stream) {
    const float* f = (const float*)d_in[0];
    const float* z = (const float*)d_in[1];
    const float* i = (const float*)d_in[2];
    float* out = (float*)d_out;

    const int rows = out_size / S_LEN;                 // B*H = 16384
    const int grid = (rows + WAVES - 1) / WAVES;       // 4096 blocks
    ifo_scan_kernel<<<grid, TPB, 0, stream>>>(f, z, i, out, rows);
}